// Round 6
// baseline (276.093 us; speedup 1.0000x reference)
//
#include <hip/hip_runtime.h>

#define EPS 1e-5
constexpr int BLOCK = 256;
constexpr int SBLOCKS = 1024;              // stats blocks per image
constexpr int TOTAL_STATS = SBLOCKS * 2;   // both images

// ---------------- 3x3 symmetric Jacobi eigendecomposition ------------------
__device__ void jacobi3(const double Ain[3][3], double w[3], double V[3][3]) {
    double A[3][3];
    for (int i = 0; i < 3; ++i)
        for (int j = 0; j < 3; ++j) {
            A[i][j] = Ain[i][j];
            V[i][j] = (i == j) ? 1.0 : 0.0;
        }
    const int pp[3] = {0, 0, 1};
    const int qq[3] = {1, 2, 2};
    for (int sweep = 0; sweep < 20; ++sweep) {
        double off = A[0][1]*A[0][1] + A[0][2]*A[0][2] + A[1][2]*A[1][2];
        if (off < 1e-28) break;
        for (int r3 = 0; r3 < 3; ++r3) {
            int p = pp[r3], q = qq[r3];
            double apq = A[p][q];
            if (apq == 0.0) continue;
            double theta = (A[q][q] - A[p][p]) / (2.0 * apq);
            double t = ((theta >= 0.0) ? 1.0 : -1.0) /
                       (fabs(theta) + sqrt(theta * theta + 1.0));
            double c = 1.0 / sqrt(t * t + 1.0);
            double s = t * c;
            A[p][p] -= t * apq;
            A[q][q] += t * apq;
            A[p][q] = A[q][p] = 0.0;
            int r = 3 - p - q;
            double arp = A[r][p], arq = A[r][q];
            A[r][p] = A[p][r] = c * arp - s * arq;
            A[r][q] = A[q][r] = s * arp + c * arq;
            for (int k = 0; k < 3; ++k) {
                double vkp = V[k][p], vkq = V[k][q];
                V[k][p] = c * vkp - s * vkq;
                V[k][q] = s * vkp + c * vkq;
            }
        }
    }
    w[0] = A[0][0]; w[1] = A[1][1]; w[2] = A[2][2];
}

// P = V * diag(f(w)) * V^T,  f = sqrt (or 1/sqrt if invert), nan/neg -> 0
__device__ void pca_pow(const double w[3], const double V[3][3], bool invert,
                        double P[3][3]) {
    double e[3];
    for (int k = 0; k < 3; ++k) {
        double ek = (w[k] > 0.0) ? sqrt(w[k]) : 0.0;
        if (invert) ek = (ek > 0.0) ? 1.0 / ek : 0.0;
        e[k] = ek;
    }
    for (int i = 0; i < 3; ++i)
        for (int j = 0; j < 3; ++j) {
            double t = 0;
            for (int k = 0; k < 3; ++k) t += V[i][k] * e[k] * V[j][k];
            P[i][j] = t;
        }
}

__device__ void solve_one(const double* a, double inv_n, bool invert,
                          double P[3][3], double mean[3]) {
    double m0 = a[0] * inv_n, m1 = a[1] * inv_n, m2 = a[2] * inv_n;
    mean[0] = m0; mean[1] = m1; mean[2] = m2;
    double C[3][3];
    C[0][0] = a[3] * inv_n - m0 * m0 + EPS;
    C[0][1] = C[1][0] = a[4] * inv_n - m0 * m1;
    C[0][2] = C[2][0] = a[5] * inv_n - m0 * m2;
    C[1][1] = a[6] * inv_n - m1 * m1 + EPS;
    C[1][2] = C[2][1] = a[7] * inv_n - m1 * m2;
    C[2][2] = a[8] * inv_n - m2 * m2 + EPS;
    double w[3], V[3][3];
    jacobi3(C, w, V);
    pca_pow(w, V, invert, P);
}

// T = sqrtm(cs) @ invsqrtm(ct); bias = mean_s - T*mean_t; -> tb[12]
__device__ void combine_tb(const double Pt[3][3], const double Ps[3][3],
                           const double mt[3], const double ms[3],
                           float* tb) {
    double T[3][3];
    for (int i = 0; i < 3; ++i)
        for (int j = 0; j < 3; ++j) {
            double t = 0;
            for (int k = 0; k < 3; ++k) t += Ps[i][k] * Pt[k][j];
            T[i][j] = t;
        }
    for (int i = 0; i < 3; ++i) {
        double b = ms[i];
        for (int k = 0; k < 3; ++k) b -= T[i][k] * mt[k];
        tb[3 * i + 0] = (float)T[i][0];
        tb[3 * i + 1] = (float)T[i][1];
        tb[3 * i + 2] = (float)T[i][2];
        tb[9 + i] = (float)b;
    }
}

// ============ kernel 1: stats + last-block reduce + solve ===================
// grid = (SBLOCKS, 2); blockIdx.y selects image.
__global__ void stats_solve_kernel(const float* __restrict__ in0,
                                   const float* __restrict__ in1,
                                   double* __restrict__ partials,  // TOTAL_STATS*9
                                   float* __restrict__ tb,         // T(9)+bias(3)
                                   unsigned* __restrict__ counter, // 1, zeroed
                                   int n4, double inv_n) {
    const int tid = threadIdx.x;
    const int lane = tid & 63;
    const int wid  = tid >> 6;
    const int img = blockIdx.y;
    __shared__ double sh[BLOCK / 64][9];

    // ---- per-block stats ----
    {
        const float4* base = (const float4*)(img ? in1 : in0);
        double s0 = 0, s1 = 0, s2 = 0;
        double q00 = 0, q01 = 0, q02 = 0, q11 = 0, q12 = 0, q22 = 0;
        const int stride = SBLOCKS * BLOCK;
        const int i0 = blockIdx.x * BLOCK + tid;
#define ACC4(a, bb, c) { \
        double x = (double)(a), y = (double)(bb), z = (double)(c);              \
        s0 += x; s1 += y; s2 += z;                                              \
        q00 = fma(x, x, q00); q01 = fma(x, y, q01); q02 = fma(x, z, q02);       \
        q11 = fma(y, y, q11); q12 = fma(y, z, q12); q22 = fma(z, z, q22); }
#define ACCV(A, B, C) ACC4(A.x, B.x, C.x) ACC4(A.y, B.y, C.y) \
                      ACC4(A.z, B.z, C.z) ACC4(A.w, B.w, C.w)
        if (n4 == 4 * stride) {
            // exact-4 path: issue all 12 independent loads up front
            const float4* p = base + i0;
            float4 a0 = p[0 * stride],          a1 = p[1 * stride];
            float4 a2 = p[2 * stride],          a3 = p[3 * stride];
            float4 b0 = p[n4 + 0 * stride],     b1 = p[n4 + 1 * stride];
            float4 b2 = p[n4 + 2 * stride],     b3 = p[n4 + 3 * stride];
            float4 c0 = p[2 * n4 + 0 * stride], c1 = p[2 * n4 + 1 * stride];
            float4 c2 = p[2 * n4 + 2 * stride], c3 = p[2 * n4 + 3 * stride];
            ACCV(a0, b0, c0) ACCV(a1, b1, c1) ACCV(a2, b2, c2) ACCV(a3, b3, c3)
        } else {
            for (int i = i0; i < n4; i += stride) {
                float4 a = base[i];
                float4 bb = base[i + n4];
                float4 c = base[i + 2 * n4];
                ACCV(a, bb, c)
            }
        }
#undef ACCV
#undef ACC4
        double v[9] = {s0, s1, s2, q00, q01, q02, q11, q12, q22};
#pragma unroll
        for (int j = 0; j < 9; ++j) {
            double t = v[j];
#pragma unroll
            for (int o = 32; o > 0; o >>= 1) t += __shfl_down(t, o, 64);
            if (lane == 0) sh[wid][j] = t;
        }
        __syncthreads();
        if (tid == 0) {
            double* outp = partials + (img * SBLOCKS + blockIdx.x) * 9;
#pragma unroll
            for (int j = 0; j < 9; ++j)
                outp[j] = sh[0][j] + sh[1][j] + sh[2][j] + sh[3][j];
        }
    }

    // ---- publish partials, elect the last block ----
    __threadfence();
    __shared__ int islast;
    if (tid == 0) {
        unsigned old = atomicAdd(counter, 1u);
        islast = (old == TOTAL_STATS - 1);
    }
    __syncthreads();
    if (!islast) return;
    __threadfence();   // acquire: all partials visible to this block

    // ---- final reduce + solve (one block; fixed order -> deterministic) ----
    __shared__ double ssum[2][9];
    __shared__ double sP[2][3][3];
    __shared__ double sMean[2][3];
    for (int im = 0; im < 2; ++im) {
        double v[9] = {0, 0, 0, 0, 0, 0, 0, 0, 0};
        for (int s = tid; s < SBLOCKS; s += BLOCK) {
            const double* p = partials + (im * SBLOCKS + s) * 9;
#pragma unroll
            for (int j = 0; j < 9; ++j) v[j] += p[j];
        }
        __syncthreads();   // sh reuse
#pragma unroll
        for (int j = 0; j < 9; ++j) {
            double t = v[j];
#pragma unroll
            for (int o = 32; o > 0; o >>= 1) t += __shfl_down(t, o, 64);
            if (lane == 0) sh[wid][j] = t;
        }
        __syncthreads();
        if (tid == 0) {
#pragma unroll
            for (int j = 0; j < 9; ++j)
                ssum[im][j] = sh[0][j] + sh[1][j] + sh[2][j] + sh[3][j];
        }
        __syncthreads();
    }
    if (tid < 2) {
        double P[3][3], mean[3];
        solve_one(ssum[tid], inv_n, tid == 0, P, mean);
        for (int i = 0; i < 3; ++i) {
            sMean[tid][i] = mean[i];
            for (int j = 0; j < 3; ++j) sP[tid][i][j] = P[i][j];
        }
    }
    __syncthreads();
    if (tid == 0) combine_tb(sP[0], sP[1], sMean[0], sMean[1], tb);
}

// ============ kernel 2: apply out = T*in + bias =============================
__global__ void apply_kernel(const float* __restrict__ in,
                             const float* __restrict__ tb,
                             float* __restrict__ out, int n4) {
    float t00 = tb[0], t01 = tb[1], t02 = tb[2];
    float t10 = tb[3], t11 = tb[4], t12 = tb[5];
    float t20 = tb[6], t21 = tb[7], t22 = tb[8];
    float b0 = tb[9], b1 = tb[10], b2 = tb[11];
    const float4* a = (const float4*)in;
    float4* o = (float4*)out;
    int stride = gridDim.x * blockDim.x;
    for (int i = blockIdx.x * blockDim.x + threadIdx.x; i < n4; i += stride) {
        float4 x = a[i];
        float4 y = a[i + n4];
        float4 z = a[i + 2 * n4];
        float4 r0, r1, r2;
#define AP(f) r0.f = fmaf(t00, x.f, fmaf(t01, y.f, fmaf(t02, z.f, b0)));       \
              r1.f = fmaf(t10, x.f, fmaf(t11, y.f, fmaf(t12, z.f, b1)));       \
              r2.f = fmaf(t20, x.f, fmaf(t21, y.f, fmaf(t22, z.f, b2)));
        AP(x) AP(y) AP(z) AP(w)
#undef AP
        o[i] = r0;
        o[i + n4] = r1;
        o[i + 2 * n4] = r2;
    }
}

extern "C" void kernel_launch(void* const* d_in, const int* in_sizes, int n_in,
                              void* d_out, int out_size, void* d_ws, size_t ws_size,
                              hipStream_t stream) {
    const float* in0 = (const float*)d_in[0];   // input (target)
    const float* in1 = (const float*)d_in[1];   // source_tensor
    float* out = (float*)d_out;
    int total = in_sizes[0];     // 3 * H * W
    int n = total / 3;           // plane size H*W
    int n4 = n / 4;              // float4 count per plane

    // ws layout: partials (TOTAL_STATS*9 doubles = 147456 B) | tb | counter
    double* partials = (double*)d_ws;
    float* tb = (float*)((char*)d_ws + 150528);
    unsigned* counter = (unsigned*)((char*)d_ws + 151552);
    double inv_n = 1.0 / (double)n;

    hipMemsetAsync(counter, 0, sizeof(unsigned), stream);

    dim3 sgrid(SBLOCKS, 2);
    stats_solve_kernel<<<sgrid, BLOCK, 0, stream>>>(in0, in1, partials, tb,
                                                    counter, n4, inv_n);
    apply_kernel<<<2048, BLOCK, 0, stream>>>(in0, tb, out, n4);
}

// Round 7
// 56.556 us; speedup vs baseline: 4.8818x; 4.8818x over previous
//
#include <hip/hip_runtime.h>

#define EPS 1e-5
constexpr int BLOCK = 256;
constexpr int SBLOCKS = 1024;   // stats blocks per image (8 blocks/CU total)

// ---------------- 3x3 symmetric Jacobi eigendecomposition ------------------
__device__ void jacobi3(const double Ain[3][3], double w[3], double V[3][3]) {
    double A[3][3];
    for (int i = 0; i < 3; ++i)
        for (int j = 0; j < 3; ++j) {
            A[i][j] = Ain[i][j];
            V[i][j] = (i == j) ? 1.0 : 0.0;
        }
    const int pp[3] = {0, 0, 1};
    const int qq[3] = {1, 2, 2};
    for (int sweep = 0; sweep < 20; ++sweep) {
        double off = A[0][1]*A[0][1] + A[0][2]*A[0][2] + A[1][2]*A[1][2];
        if (off < 1e-28) break;
        for (int r3 = 0; r3 < 3; ++r3) {
            int p = pp[r3], q = qq[r3];
            double apq = A[p][q];
            if (apq == 0.0) continue;
            double theta = (A[q][q] - A[p][p]) / (2.0 * apq);
            double t = ((theta >= 0.0) ? 1.0 : -1.0) /
                       (fabs(theta) + sqrt(theta * theta + 1.0));
            double c = 1.0 / sqrt(t * t + 1.0);
            double s = t * c;
            A[p][p] -= t * apq;
            A[q][q] += t * apq;
            A[p][q] = A[q][p] = 0.0;
            int r = 3 - p - q;
            double arp = A[r][p], arq = A[r][q];
            A[r][p] = A[p][r] = c * arp - s * arq;
            A[r][q] = A[q][r] = s * arp + c * arq;
            for (int k = 0; k < 3; ++k) {
                double vkp = V[k][p], vkq = V[k][q];
                V[k][p] = c * vkp - s * vkq;
                V[k][q] = s * vkp + c * vkq;
            }
        }
    }
    w[0] = A[0][0]; w[1] = A[1][1]; w[2] = A[2][2];
}

// P = V * diag(f(w)) * V^T,  f = sqrt (or 1/sqrt if invert), nan/neg -> 0
__device__ void pca_pow(const double w[3], const double V[3][3], bool invert,
                        double P[3][3]) {
    double e[3];
    for (int k = 0; k < 3; ++k) {
        double ek = (w[k] > 0.0) ? sqrt(w[k]) : 0.0;
        if (invert) ek = (ek > 0.0) ? 1.0 / ek : 0.0;
        e[k] = ek;
    }
    for (int i = 0; i < 3; ++i)
        for (int j = 0; j < 3; ++j) {
            double t = 0;
            for (int k = 0; k < 3; ++k) t += V[i][k] * e[k] * V[j][k];
            P[i][j] = t;
        }
}

__device__ void solve_one(const double* a, double inv_n, bool invert,
                          double P[3][3], double mean[3]) {
    double m0 = a[0] * inv_n, m1 = a[1] * inv_n, m2 = a[2] * inv_n;
    mean[0] = m0; mean[1] = m1; mean[2] = m2;
    double C[3][3];
    C[0][0] = a[3] * inv_n - m0 * m0 + EPS;
    C[0][1] = C[1][0] = a[4] * inv_n - m0 * m1;
    C[0][2] = C[2][0] = a[5] * inv_n - m0 * m2;
    C[1][1] = a[6] * inv_n - m1 * m1 + EPS;
    C[1][2] = C[2][1] = a[7] * inv_n - m1 * m2;
    C[2][2] = a[8] * inv_n - m2 * m2 + EPS;
    double w[3], V[3][3];
    jacobi3(C, w, V);
    pca_pow(w, V, invert, P);
}

// T = sqrtm(cs) @ invsqrtm(ct); bias = mean_s - T*mean_t; -> tb[12]
__device__ void combine_tb(const double Pt[3][3], const double Ps[3][3],
                           const double mt[3], const double ms[3],
                           float* tb) {
    double T[3][3];
    for (int i = 0; i < 3; ++i)
        for (int j = 0; j < 3; ++j) {
            double t = 0;
            for (int k = 0; k < 3; ++k) t += Ps[i][k] * Pt[k][j];
            T[i][j] = t;
        }
    for (int i = 0; i < 3; ++i) {
        double b = ms[i];
        for (int k = 0; k < 3; ++k) b -= T[i][k] * mt[k];
        tb[3 * i + 0] = (float)T[i][0];
        tb[3 * i + 1] = (float)T[i][1];
        tb[3 * i + 2] = (float)T[i][2];
        tb[9 + i] = (float)b;
    }
}

// ============ kernel 1: per-block stats (no fences, no atomics) =============
// grid = (SBLOCKS, 2); blockIdx.y selects image.
__global__ void stats_kernel(const float* __restrict__ in0,
                             const float* __restrict__ in1,
                             double* __restrict__ partials, int n4) {
    const int tid = threadIdx.x;
    const int lane = tid & 63;
    const int wid  = tid >> 6;
    const float4* base = (const float4*)(blockIdx.y ? in1 : in0);
    double s0 = 0, s1 = 0, s2 = 0;
    double q00 = 0, q01 = 0, q02 = 0, q11 = 0, q12 = 0, q22 = 0;
    const int stride = SBLOCKS * BLOCK;
    for (int i = blockIdx.x * BLOCK + tid; i < n4; i += stride) {
        float4 a = base[i];
        float4 b = base[i + n4];
        float4 c = base[i + 2 * n4];
#define ACC(f) { double x = (double)a.f, y = (double)b.f, z = (double)c.f;      \
        s0 += x; s1 += y; s2 += z;                                              \
        q00 = fma(x, x, q00); q01 = fma(x, y, q01); q02 = fma(x, z, q02);       \
        q11 = fma(y, y, q11); q12 = fma(y, z, q12); q22 = fma(z, z, q22); }
        ACC(x) ACC(y) ACC(z) ACC(w)
#undef ACC
    }
    double v[9] = {s0, s1, s2, q00, q01, q02, q11, q12, q22};
    __shared__ double sh[BLOCK / 64][9];
#pragma unroll
    for (int j = 0; j < 9; ++j) {
        double t = v[j];
#pragma unroll
        for (int o = 32; o > 0; o >>= 1) t += __shfl_down(t, o, 64);
        if (lane == 0) sh[wid][j] = t;
    }
    __syncthreads();
    if (tid == 0) {
        double* outp = partials + (blockIdx.y * SBLOCKS + blockIdx.x) * 9;
#pragma unroll
        for (int j = 0; j < 9; ++j)
            outp[j] = sh[0][j] + sh[1][j] + sh[2][j] + sh[3][j];
    }
}

// ============ kernel 2: reduce partials + solve -> tb =======================
__global__ void solve_kernel(const double* __restrict__ partials,
                             float* __restrict__ tb, double inv_n) {
    __shared__ double ssum[2][9];
    __shared__ double sP[2][3][3];
    __shared__ double sMean[2][3];
    __shared__ double sh[BLOCK / 64][9];
    const int tid = threadIdx.x;
    const int lane = tid & 63;
    const int wid  = tid >> 6;
    for (int im = 0; im < 2; ++im) {
        double v[9] = {0, 0, 0, 0, 0, 0, 0, 0, 0};
        for (int s = tid; s < SBLOCKS; s += BLOCK) {
            const double* p = partials + (im * SBLOCKS + s) * 9;
#pragma unroll
            for (int j = 0; j < 9; ++j) v[j] += p[j];
        }
#pragma unroll
        for (int j = 0; j < 9; ++j) {
            double t = v[j];
#pragma unroll
            for (int o = 32; o > 0; o >>= 1) t += __shfl_down(t, o, 64);
            if (lane == 0) sh[wid][j] = t;
        }
        __syncthreads();
        if (tid == 0) {
#pragma unroll
            for (int j = 0; j < 9; ++j)
                ssum[im][j] = sh[0][j] + sh[1][j] + sh[2][j] + sh[3][j];
        }
        __syncthreads();
    }
    if (tid < 2) {
        double P[3][3], mean[3];
        solve_one(ssum[tid], inv_n, tid == 0, P, mean);
        for (int i = 0; i < 3; ++i) {
            sMean[tid][i] = mean[i];
            for (int j = 0; j < 3; ++j) sP[tid][i][j] = P[i][j];
        }
    }
    __syncthreads();
    if (tid == 0) combine_tb(sP[0], sP[1], sMean[0], sMean[1], tb);
}

// ============ kernel 3: apply out = T*in + bias =============================
__global__ void apply_kernel(const float* __restrict__ in,
                             const float* __restrict__ tb,
                             float* __restrict__ out, int n4) {
    float t00 = tb[0], t01 = tb[1], t02 = tb[2];
    float t10 = tb[3], t11 = tb[4], t12 = tb[5];
    float t20 = tb[6], t21 = tb[7], t22 = tb[8];
    float b0 = tb[9], b1 = tb[10], b2 = tb[11];
    const float4* a = (const float4*)in;
    float4* o = (float4*)out;
    int stride = gridDim.x * blockDim.x;
    for (int i = blockIdx.x * blockDim.x + threadIdx.x; i < n4; i += stride) {
        float4 x = a[i];
        float4 y = a[i + n4];
        float4 z = a[i + 2 * n4];
        float4 r0, r1, r2;
#define AP(f) r0.f = fmaf(t00, x.f, fmaf(t01, y.f, fmaf(t02, z.f, b0)));       \
              r1.f = fmaf(t10, x.f, fmaf(t11, y.f, fmaf(t12, z.f, b1)));       \
              r2.f = fmaf(t20, x.f, fmaf(t21, y.f, fmaf(t22, z.f, b2)));
        AP(x) AP(y) AP(z) AP(w)
#undef AP
        o[i] = r0;
        o[i + n4] = r1;
        o[i + 2 * n4] = r2;
    }
}

extern "C" void kernel_launch(void* const* d_in, const int* in_sizes, int n_in,
                              void* d_out, int out_size, void* d_ws, size_t ws_size,
                              hipStream_t stream) {
    const float* in0 = (const float*)d_in[0];   // input (target)
    const float* in1 = (const float*)d_in[1];   // source_tensor
    float* out = (float*)d_out;
    int total = in_sizes[0];     // 3 * H * W
    int n = total / 3;           // plane size H*W
    int n4 = n / 4;              // float4 count per plane

    // ws layout: partials (2*SBLOCKS*9 doubles = 147456 B) | tb
    double* partials = (double*)d_ws;
    float* tb = (float*)((char*)d_ws + 150528);
    double inv_n = 1.0 / (double)n;

    dim3 sgrid(SBLOCKS, 2);
    stats_kernel<<<sgrid, BLOCK, 0, stream>>>(in0, in1, partials, n4);
    solve_kernel<<<1, BLOCK, 0, stream>>>(partials, tb, inv_n);
    apply_kernel<<<2048, BLOCK, 0, stream>>>(in0, tb, out, n4);
}